// Round 10
// baseline (3755.538 us; speedup 1.0000x reference)
//
#include <hip/hip_runtime.h>
#include <math.h>

// LSTM H=1024, T=2048, IN=5, OUT=9, batch=1 on MI355X.
// R8 structure + REPLICATED ring to cut same-line poll concurrency:
//   ring[slot 0..3][replica 0..R-1][512 atoms]; atom = (tag u32 | 2x bf16).
//   Consumer WG c polls replica (c & (R-1)) only -> 64/R readers per line.
//   Producer wave7 writes ALL replicas with ONE wave store: lane k writes
//   replica k>>3, atom (pid*8 + (k&7)) -> 8 disjoint full 64B lines,
//   no partial-line RMW (R7 invariant preserved).
// R chosen host-side from ws_size (8/4/2/1); R=1 == R8 exactly.
// Also: fast transcendentals (__expf/__fdividef) in the finisher, and
// float4 LDS reads in the matvec (128 -> 32 LDS ops).

typedef unsigned int u32;
typedef unsigned long long u64;

constexpr int kH     = 1024;
constexpr int kT     = 2048;
constexpr int kIN    = 5;
constexpr int kOUT   = 9;
constexpr int kNWG   = 64;
constexpr int kBLOCK = 512;

__device__ __forceinline__ float sigm_(float v) {
  return __fdividef(1.0f, 1.0f + __expf(-v));
}
__device__ __forceinline__ float tanh_(float v) {
  return 1.0f - __fdividef(2.0f, __expf(2.0f * v) + 1.0f);
}
__device__ __forceinline__ u32 bf16_rne(float f) {
  u32 b = __float_as_uint(f);
  return (b + 0x7FFFu + ((b >> 16) & 1u)) >> 16;
}
__device__ __forceinline__ float lo_f(u32 p) { return __uint_as_float(p << 16); }
__device__ __forceinline__ float hi_f(u32 p) { return __uint_as_float(p & 0xFFFF0000u); }

// One poll sample: 8B/lane, wave-coalesced 512B, LLC-coherent.
__device__ __forceinline__ u64 poll1(const u64* p) {
  u64 a;
  asm volatile(
      "global_load_dwordx2 %0, %1, off sc0 sc1\n\t"
      "s_waitcnt vmcnt(0)"
      : "=v"(a) : "v"(p) : "memory");
  return a;
}

// Epilogue-only: 8 x 8B at 512B stride (atoms lane + 64m), one drain.
__device__ __forceinline__ void poll8(const u64* p, u64& a0, u64& a1, u64& a2,
                                      u64& a3, u64& a4, u64& a5, u64& a6,
                                      u64& a7) {
  asm volatile(
      "global_load_dwordx2 %0, %8, off sc0 sc1\n\t"
      "global_load_dwordx2 %1, %8, off offset:512 sc0 sc1\n\t"
      "global_load_dwordx2 %2, %8, off offset:1024 sc0 sc1\n\t"
      "global_load_dwordx2 %3, %8, off offset:1536 sc0 sc1\n\t"
      "global_load_dwordx2 %4, %8, off offset:2048 sc0 sc1\n\t"
      "global_load_dwordx2 %5, %8, off offset:2560 sc0 sc1\n\t"
      "global_load_dwordx2 %6, %8, off offset:3072 sc0 sc1\n\t"
      "global_load_dwordx2 %7, %8, off offset:3584 sc0 sc1\n\t"
      "s_waitcnt vmcnt(0)"
      : "=&v"(a0), "=&v"(a1), "=&v"(a2), "=&v"(a3),
        "=&v"(a4), "=&v"(a5), "=&v"(a6), "=&v"(a7)
      : "v"(p)
      : "memory");
}

__global__ __launch_bounds__(kBLOCK, 2) void lstm_v9(
    const float* __restrict__ x,     // [T,1,IN]
    const float* __restrict__ w_ih,  // [4H,IN]
    const float* __restrict__ w_hh,  // [4H,H]
    const float* __restrict__ b_ih,  // [4H]
    const float* __restrict__ b_hh,  // [4H]
    const float* __restrict__ w_out, // [OUT,H]
    const float* __restrict__ b_out, // [OUT]
    float* __restrict__ out,         // [OUT]
    u64* __restrict__ ring,          // ring[4][R][512]
    u32 slotStride,                  // R*512 (u64 units)
    u32 repMask,                     // R-1
    u32 pubLanes) {                  // 8*R
  const int pid  = blockIdx.x;
  const int tid  = threadIdx.x;
  const int w    = tid >> 6;
  const int lane = tid & 63;

  __shared__ float x_lds[kT * kIN];           // 40 KiB
  __shared__ __align__(16) float h_lds[kH];   // 4 KiB; wave w owns [128w,+128)
  __shared__ float pacc[2][7][64];            // partials, dbuf by t&1
  __shared__ int   gcnt;                      // monotonic counter

  for (int i = tid; i < kT * kIN; i += kBLOCK) x_lds[i] = x[i];
  if (tid == 0) gcnt = 0;

  // Lane l owns gate-row l: gate g = l>>4 ([i,f,g,o]), j = l&15.
  const int grow = (lane >> 4) * kH + pid * 16 + (lane & 15);
  const int cb   = 128 * w;  // this wave's h-column slice base

  float wreg[128];
  {
    const float* sp = w_hh + (size_t)grow * kH + cb;
#pragma unroll
    for (int m = 0; m < 128; m += 4) {
      const float4 v4 = *(const float4*)(sp + m);
      wreg[m] = v4.x; wreg[m + 1] = v4.y; wreg[m + 2] = v4.z; wreg[m + 3] = v4.w;
    }
  }
  float wihr[kIN];
#pragma unroll
  for (int k = 0; k < kIN; ++k) wihr[k] = w_ih[grow * kIN + k];
  const float biasr = b_ih[grow] + b_hh[grow];

  const u32 myRep = (u32)pid & repMask;
  float cst = 0.0f;  // wave7: cell state for j = lane&15
  __syncthreads();   // x_lds + gcnt ready — only barrier in the kernel

  for (int t = 0; t < kT; ++t) {
    // gx for row `lane` — before the wait
    float gx = biasr;
#pragma unroll
    for (int k = 0; k < kIN; ++k) gx = fmaf(wihr[k], x_lds[t * kIN + k], gx);

    // ---- poll own slice in own replica: atom 64w+lane ----
    const u64* pb = ring + (size_t)(t & 3) * slotStride + myRep * 512 +
                    64 * w + lane;
    u64 a;
    do {
      a = poll1(pb);
    } while (!__all((u32)(a >> 32) == (u32)t));

    // unpack into this wave's private h segment: atom -> cols {cb+2l, +1}
    const u32 d = (u32)a;
    *(float2*)&h_lds[cb + 2 * lane] = make_float2(lo_f(d), hi_f(d));

    // ---- partial matvec: row `lane` x cols [cb, cb+128), float4 reads ----
    float acc0 = 0.0f, acc1 = 0.0f, acc2 = 0.0f, acc3 = 0.0f;
#pragma unroll
    for (int m = 0; m < 128; m += 4) {
      const float4 h4 = *(const float4*)&h_lds[cb + m];
      acc0 = fmaf(wreg[m + 0], h4.x, acc0);
      acc1 = fmaf(wreg[m + 1], h4.y, acc1);
      acc2 = fmaf(wreg[m + 2], h4.z, acc2);
      acc3 = fmaf(wreg[m + 3], h4.w, acc3);
    }
    const float part = (acc0 + acc1) + (acc2 + acc3);

    if (w < 7) {
      pacc[t & 1][w][lane] = part;
      if (lane == 0)
        __hip_atomic_fetch_add(&gcnt, 1, __ATOMIC_RELEASE,
                               __HIP_MEMORY_SCOPE_WORKGROUP);
    } else {
      // ---- finisher ----
      while (__hip_atomic_load(&gcnt, __ATOMIC_ACQUIRE,
                               __HIP_MEMORY_SCOPE_WORKGROUP) < 7 * (t + 1)) { }
      float gtot = part + gx;
#pragma unroll
      for (int w2 = 0; w2 < 7; ++w2) gtot += pacc[t & 1][w2][lane];

      const int gate = lane >> 4;        // [i,f,g,o]; g -> tanh
      const float u = (gate == 2) ? 2.0f * gtot : gtot;
      float n = sigm_(u);
      n = (gate == 2) ? (2.0f * n - 1.0f) : n;

      const int j = lane & 15;
      const float ni = __shfl(n, j);
      const float nf = __shfl(n, 16 + j);
      const float ng = __shfl(n, 32 + j);
      const float no = __shfl(n, 48 + j);
      cst = nf * cst + ni * ng;
      const float hval = no * tanh_(cst);

      // publish to ALL replicas with one wave store:
      // lane k -> replica k>>3, atom pid*8 + (k&7): 8 disjoint full lines.
      const int al = lane & 7;
      const float ph0 = __shfl(hval, 2 * al);      // j = 2*al
      const float ph1 = __shfl(hval, 2 * al + 1);  // j = 2*al+1
      if (lane < (int)pubLanes) {
        const u64 atom = ((u64)(u32)(t + 1) << 32) |
                         (u64)(bf16_rne(ph0) | (bf16_rne(ph1) << 16));
        __hip_atomic_store(ring + (size_t)((t + 1) & 3) * slotStride +
                               (size_t)(lane >> 3) * 512 + pid * 8 + al,
                           atom, __ATOMIC_RELAXED, __HIP_MEMORY_SCOPE_AGENT);
      }
    }
  }

  // ---- epilogue: tanh -> 9x1024 matvec -> log_softmax (WG0 wave0) ----
  if (pid == 0 && w == 0) {
    const u64* pb = ring + (size_t)(kT & 3) * slotStride + lane;  // replica 0
    u64 a0, a1, a2, a3, a4, a5, a6, a7;
    bool ok;
    do {
      poll8(pb, a0, a1, a2, a3, a4, a5, a6, a7);
      ok = ((u32)(a0 >> 32) == (u32)kT) & ((u32)(a1 >> 32) == (u32)kT) &
           ((u32)(a2 >> 32) == (u32)kT) & ((u32)(a3 >> 32) == (u32)kT) &
           ((u32)(a4 >> 32) == (u32)kT) & ((u32)(a5 >> 32) == (u32)kT) &
           ((u32)(a6 >> 32) == (u32)kT) & ((u32)(a7 >> 32) == (u32)kT);
    } while (!__all(ok));

    u64 av[8] = {a0, a1, a2, a3, a4, a5, a6, a7};
    float logits[kOUT];
#pragma unroll
    for (int r = 0; r < kOUT; ++r) logits[r] = 0.0f;
#pragma unroll
    for (int m = 0; m < 8; ++m) {
      const u32 d = (u32)av[m];
      const float z0 = tanhf(lo_f(d));
      const float z1 = tanhf(hi_f(d));
      const int col = 2 * lane + 128 * m;
#pragma unroll
      for (int r = 0; r < kOUT; ++r) {
        const float2 wv = *(const float2*)(w_out + (size_t)r * kH + col);
        logits[r] = fmaf(wv.x, z0, fmaf(wv.y, z1, logits[r]));
      }
    }
#pragma unroll
    for (int r = 0; r < kOUT; ++r) {
#pragma unroll
      for (int off = 32; off; off >>= 1)
        logits[r] += __shfl_xor(logits[r], off);
      logits[r] += b_out[r];
    }
    if (lane == 0) {
      float m = logits[0];
#pragma unroll
      for (int r = 1; r < kOUT; ++r) m = fmaxf(m, logits[r]);
      float s = 0.0f;
#pragma unroll
      for (int r = 0; r < kOUT; ++r) s += expf(logits[r] - m);
      const float lse = m + logf(s);
#pragma unroll
      for (int r = 0; r < kOUT; ++r) out[r] = logits[r] - lse;
    }
  }
}

extern "C" void kernel_launch(void* const* d_in, const int* in_sizes, int n_in,
                              void* d_out, int out_size, void* d_ws, size_t ws_size,
                              hipStream_t stream) {
  const float* x     = (const float*)d_in[0];
  const float* w_ih  = (const float*)d_in[1];
  const float* w_hh  = (const float*)d_in[2];
  const float* b_ih  = (const float*)d_in[3];
  const float* b_hh  = (const float*)d_in[4];
  const float* w_out = (const float*)d_in[5];
  const float* b_out = (const float*)d_in[6];
  float* out  = (float*)d_out;
  u64*   ring = (u64*)d_ws;

  // Replica count from workspace budget: 4 slots x R x 4KB.
  int R = 1;
  if      (ws_size >= 4ull * 8 * 4096) R = 8;
  else if (ws_size >= 4ull * 4 * 4096) R = 4;
  else if (ws_size >= 4ull * 2 * 4096) R = 2;
  const u32 slotStride = (u32)(R * 512);  // u64 units

  // Zero the whole ring each call (slot0 tag0/h0 = 0; clear stale tags).
  hipMemsetAsync(d_ws, 0, (size_t)4 * slotStride * sizeof(u64), stream);

  lstm_v9<<<kNWG, kBLOCK, 0, stream>>>(x, w_ih, w_hh, b_ih, b_hh,
                                       w_out, b_out, out, ring,
                                       slotStride, (u32)(R - 1), (u32)(8 * R));
}